// Round 6
// baseline (276.522 us; speedup 1.0000x reference)
//
#include <hip/hip_runtime.h>
#include <math.h>

// B=2048 rows, L=16384, W=30 sliding mean of sigmoid(x)*mask, per-row max.
// R6: deep-MLP staging via global_load_lds (width 16, no VGPR round trip,
// ~9 outstanding 1KB DMAs per wave) + R5's verified DPP-scan/bpermute window
// machinery reading b128 from LDS. One barrier per block; its vmcnt(0) drain
// is the DMA completion guarantee.
constexpr int Bn   = 2048;
constexpr int L    = 16384;
constexpr int W    = 30;
constexpr int NT   = 256;
constexpr int TILE = 4096;            // window-ENDS per block
constexpr int TPB  = L / TILE;        // 4 blocks per row
constexpr int NCHK = TILE / 256 + 1;  // 17 chunks incl. 256-float front halo

template <int CTRL, int RMASK>
__device__ __forceinline__ float dpp_add(float x) {
    int s = __builtin_amdgcn_update_dpp(0, __float_as_int(x), CTRL, RMASK, 0xf, false);
    return x + __int_as_float(s);
}

// wave64 inclusive +scan
__device__ __forceinline__ float wave_iscan(float x) {
    x = dpp_add<0x111, 0xf>(x);   // row_shr:1
    x = dpp_add<0x112, 0xf>(x);   // row_shr:2
    x = dpp_add<0x114, 0xf>(x);   // row_shr:4
    x = dpp_add<0x118, 0xf>(x);   // row_shr:8
    x = dpp_add<0x142, 0xa>(x);   // row_bcast:15 -> rows 1,3
    x = dpp_add<0x143, 0xc>(x);   // row_bcast:31 -> rows 2,3
    return x;
}

__device__ __forceinline__ float bperm(int byteaddr, float v) {
    return __int_as_float(__builtin_amdgcn_ds_bpermute(byteaddr, __float_as_int(v)));
}

__device__ __forceinline__ float sigp(float xv, float mv) {
    return mv * __builtin_amdgcn_rcpf(1.0f + __builtin_amdgcn_exp2f(-1.44269504089f * xv));
}

// Inclusive within-chunk prefixes at this lane's elements 4l..4l+3.
__device__ __forceinline__ void chunk_prefix(float4 xv, float4 mv,
                                             float& u0, float& u1, float& u2, float& u3) {
    float p0 = sigp(xv.x, mv.x);
    float p1 = sigp(xv.y, mv.y);
    float p2 = sigp(xv.z, mv.z);
    float p3 = sigp(xv.w, mv.w);
    float T  = (p0 + p1) + (p2 + p3);
    float inc = wave_iscan(T);
    u3 = inc;
    u2 = inc - p3;
    u1 = u2 - p2;
    u0 = u1 - p1;
}

#define AS_GLOBAL(p) ((const __attribute__((address_space(1))) void*)(p))
#define AS_LDS(p)    ((__attribute__((address_space(3))) void*)(p))

__global__ __launch_bounds__(NT, 4)
void winmax_dma(const float* __restrict__ x,
                const float* __restrict__ m,
                float* __restrict__ out) {
    __shared__ float lx[NCHK * 256];   // 17.4 KiB raw x
    __shared__ float lm[NCHK * 256];   // 17.4 KiB raw m

    const int b    = blockIdx.x;
    const int row  = b >> 2;           // TPB = 4
    const int tile = b & 3;
    const int w    = threadIdx.x >> 6;
    const int lane = threadIdx.x & 63;
    const int ts   = tile * TILE;
    const size_t rb = (size_t)row * L;

    // ---- DMA stage: chunk c = global floats [ts-256+256c .. +255] ----
    // Front halo (c=0) is the previous 256 elements (window history);
    // tile==0 skips it (register zeros below = reference zero-pad).
    {
        const float* gx = x + rb + ts - 256;
        const float* gm = m + rb + ts - 256;
        for (int c = w; c < NCHK; c += 4) {          // 4-5 chunk-pairs per wave
            if (tile == 0 && c == 0) continue;       // wave-uniform skip (OOB)
            const float* px = gx + c * 256 + lane * 4;
            const float* pm = gm + c * 256 + lane * 4;
            __builtin_amdgcn_global_load_lds(AS_GLOBAL(px), AS_LDS(&lx[c * 256]), 16, 0, 0);
            __builtin_amdgcn_global_load_lds(AS_GLOBAL(pm), AS_LDS(&lm[c * 256]), 16, 0, 0);
        }
    }
    __syncthreads();   // compiler emits s_waitcnt vmcnt(0) first: DMA complete

    // ---- Windows via chunk prefix scans (R5 machinery, verified) ----
    // Wave w owns window-ENDS in chunks 4w+1 .. 4w+4; warmup = chunk 4w.
    const int  a8 = ((lane - 8) & 63) << 2;
    const int  a7 = ((lane - 7) & 63) << 2;
    const bool c8 = (lane >= 56);
    const bool c7 = (lane >= 57);

    float pu0 = 0.f, pu1 = 0.f, pu2 = 0.f, pu3 = 0.f, D = 0.f;
    if (!(tile == 0 && w == 0)) {
        const int off = (4 * w) * 256 + 4 * lane;
        float4 wx = *(const float4*)&lx[off];        // ds_read_b128, conflict-free
        float4 wm = *(const float4*)&lm[off];
        chunk_prefix(wx, wm, pu0, pu1, pu2, pu3);
        D = bperm(63 << 2, pu3);
    }

    float best = 0.0f;
    #pragma unroll
    for (int k = 0; k < 4; ++k) {
        const int off = (4 * w + 1 + k) * 256 + 4 * lane;
        float4 cx = *(const float4*)&lx[off];
        float4 cm = *(const float4*)&lm[off];
        float u0, u1, u2, u3;
        chunk_prefix(cx, cm, u0, u1, u2, u3);
        float tot = bperm(63 << 2, u3);

        // Window ending at elem 4l+c needs prefix 30 back: lanes l-8 (c=0,1)
        // and l-7 (c=2,3); wrapped requests served by high lanes publishing
        // prev-chunk prefixes rebased by -D.
        float s8a = c8 ? (pu2 - D) : u2;
        float s8b = c8 ? (pu3 - D) : u3;
        float s7a = c7 ? (pu0 - D) : u0;
        float s7b = c7 ? (pu1 - D) : u1;
        float x0 = bperm(a8, s8a);
        float x1 = bperm(a8, s8b);
        float x2 = bperm(a7, s7a);
        float x3 = bperm(a7, s7b);

        float S0 = u0 - x0, S1 = u1 - x1, S2 = u2 - x2, S3 = u3 - x3;
        best = fmaxf(best, fmaxf(fmaxf(S0, S1), fmaxf(S2, S3)));

        pu0 = u0; pu1 = u1; pu2 = u2; pu3 = u3; D = tot;
    }
    best *= (1.0f / W);

    // ---- Wave max-reduce, one atomic per wave (win_mean >= 0) ----
    #pragma unroll
    for (int d = 1; d < 64; d <<= 1)
        best = fmaxf(best, __shfl_xor(best, d, 64));
    if (lane == 0)
        atomicMax((unsigned int*)(out + row), __float_as_uint(best));
}

extern "C" void kernel_launch(void* const* d_in, const int* in_sizes, int n_in,
                              void* d_out, int out_size, void* d_ws, size_t ws_size,
                              hipStream_t stream) {
    const float* x = (const float*)d_in[0];
    const float* m = (const float*)d_in[1];
    float* out = (float*)d_out;
    (void)hipMemsetAsync(out, 0, Bn * sizeof(float), stream);  // atomicMax needs 0-init
    winmax_dma<<<Bn * TPB, NT, 0, stream>>>(x, m, out);
}